// Round 2
// baseline (1008.599 us; speedup 1.0000x reference)
//
#include <hip/hip_runtime.h>
#include <hip/hip_bf16.h>
#include <stdint.h>

// Problem constants (B, Sq, Skv, Hq, Hkv, D) = (2, 2048, 2048, 16, 4, 128)
static constexpr int B_   = 2;
static constexpr int SQ   = 2048;
static constexpr int SKV  = 2048;
static constexpr int HQ   = 16;
static constexpr int HKV  = 4;
static constexpr int DH   = 128;

static constexpr int BM = 64;   // q rows per workgroup (16 per wave x 4 waves)
static constexpr int BN = 64;   // kv cols per iteration

static constexpr int KLD = DH + 8;  // 136 elems: K tile LDS row stride
static constexpr int VLD = BN + 8;  // 72 elems:  Vt tile LDS row stride (row = d)
static constexpr int PLD = BN + 4;  // 68 fp32:   P tile LDS row stride

#define LOG2E 1.44269504f
static constexpr float SM_SCALE = 0.08838834764831845f;  // 1/sqrt(128)

typedef unsigned short ushort_t;
typedef __attribute__((ext_vector_type(8))) short bf16x8;   // 8 bf16 in 4 VGPRs
typedef __attribute__((ext_vector_type(4))) short bf16x4;   // 4 bf16 in 2 VGPRs
typedef __attribute__((ext_vector_type(4))) float f32x4;

__device__ __forceinline__ ushort_t f2bf(float f) {
    union { float f; unsigned int i; } c; c.f = f;
    unsigned int i = c.i;
    i = i + 0x7FFF + ((i >> 16) & 1);   // RNE (finite values only here)
    return (ushort_t)(i >> 16);
}

extern "C" __global__ __launch_bounds__(256, 2)
void fa_fwd(const float* __restrict__ q, const float* __restrict__ k,
            const float* __restrict__ v, const float* __restrict__ mask,
            float* __restrict__ out)
{
    __shared__ __align__(16) ushort_t lK[BN * KLD];       // K tile bf16, row-major [kv][d]
    __shared__ __align__(16) ushort_t lV[DH * VLD];       // V tile bf16, transposed [d][kv]
    __shared__ __align__(16) float    lP[4 * 16 * PLD];   // per-wave P relayout buffers

    const int qblk = blockIdx.x;
    const int h    = blockIdx.y;
    const int b    = blockIdx.z;
    const int hk   = h & (HKV - 1);         // GQA head map: h % Hkv
    const int tid  = threadIdx.x;
    const int wave = tid >> 6;
    const int lane = tid & 63;
    const int lrow = lane & 15;             // M/N index inside MFMA tile
    const int quad = lane >> 4;
    const int q0   = qblk * BM;

    // ---- Q fragments (A-operand layout): Q[q0+wave*16+lrow][32*s + quad*8 + j], fp32 -> bf16
    const size_t qbase = ((size_t)((b * SQ + q0 + wave * 16 + lrow) * HQ + h)) * DH;
    bf16x8 qf[4];
#pragma unroll
    for (int s = 0; s < 4; ++s) {
        const f32x4 a = *(const f32x4*)(q + qbase + s * 32 + quad * 8);
        const f32x4 c = *(const f32x4*)(q + qbase + s * 32 + quad * 8 + 4);
#pragma unroll
        for (int j = 0; j < 4; ++j) {
            qf[s][j]     = (short)f2bf(a[j]);
            qf[s][j + 4] = (short)f2bf(c[j]);
        }
    }

    f32x4 oacc[8];
#pragma unroll
    for (int i = 0; i < 8; ++i) oacc[i] = (f32x4){0.f, 0.f, 0.f, 0.f};
    float mrow[4] = {-1e30f, -1e30f, -1e30f, -1e30f};
    float lsum[4] = {0.f, 0.f, 0.f, 0.f};

    float* lPw = lP + wave * 16 * PLD;

    const int niter = qblk + 1;             // causal: kv tiles 0..q0/BN
    for (int it = 0; it < niter; ++it) {
        const int kv0 = it * BN;

        __syncthreads();  // protect previous tile's LDS reads before overwrite
        // ---- stage K (row-major) and V (transposed) bf16 tiles from fp32 global
        //      64 rows x 128 d = 8192 elems = 2048 float4 chunks, 8 per thread
#pragma unroll
        for (int i = 0; i < 8; ++i) {
            const int idx = tid + i * 256;
            const int r = idx >> 5;                // kv row 0..63
            const int c = (idx & 31) * 4;          // d offset 0..124
            const size_t g = ((size_t)((b * SKV + kv0 + r) * HKV + hk)) * DH + c;
            const f32x4 kx = *(const f32x4*)(k + g);
            const f32x4 vx = *(const f32x4*)(v + g);
            bf16x4 kb;
#pragma unroll
            for (int j = 0; j < 4; ++j) kb[j] = (short)f2bf(kx[j]);
            *(bf16x4*)&lK[r * KLD + c] = kb;
#pragma unroll
            for (int j = 0; j < 4; ++j)
                lV[(c + j) * VLD + r] = f2bf(vx[j]);
        }
        __syncthreads();

        // ---- S = Q K^T : 16 rows x 64 cols per wave (4 n-subtiles, K=128 in 4 steps)
        f32x4 S[4];
#pragma unroll
        for (int n = 0; n < 4; ++n) {
            f32x4 acc = (f32x4){0.f, 0.f, 0.f, 0.f};
#pragma unroll
            for (int s = 0; s < 4; ++s) {
                const bf16x8 kf = *(const bf16x8*)&lK[(n * 16 + lrow) * KLD + s * 32 + quad * 8];
                acc = __builtin_amdgcn_mfma_f32_16x16x32_bf16(qf[s], kf, acc, 0, 0, 0);
            }
            S[n] = acc;
        }

        // ---- scale + additive mask (+ causal bias on diagonal tile), in exp2 space
        const bool diag = (kv0 == q0);
#pragma unroll
        for (int r = 0; r < 4; ++r) {
            const int row = q0 + wave * 16 + quad * 4 + r;
            const float* mp = mask + ((size_t)((b * HQ + h)) * SQ + row) * SKV + kv0;
#pragma unroll
            for (int n = 0; n < 4; ++n) {
                const int col = n * 16 + lrow;
                float s2 = S[n][r] * (SM_SCALE * LOG2E) + mp[col] * LOG2E;
                if (diag && (kv0 + col > row)) s2 -= 1000000.0f;
                S[n][r] = s2;
            }
        }

        // ---- online softmax (each row lives across the 16 lanes of one quad)
#pragma unroll
        for (int r = 0; r < 4; ++r) {
            float tm = fmaxf(fmaxf(S[0][r], S[1][r]), fmaxf(S[2][r], S[3][r]));
#pragma unroll
            for (int off = 1; off < 16; off <<= 1)
                tm = fmaxf(tm, __shfl_xor(tm, off, 64));
            const float mnew  = fmaxf(mrow[r], tm);
            const float alpha = exp2f(mrow[r] - mnew);
            mrow[r] = mnew;
            float psum = 0.f;
#pragma unroll
            for (int n = 0; n < 4; ++n) {
                const float p = exp2f(S[n][r] - mnew);
                S[n][r] = p;
                psum += p;
            }
#pragma unroll
            for (int off = 1; off < 16; off <<= 1)
                psum += __shfl_xor(psum, off, 64);
            lsum[r] = lsum[r] * alpha + psum;
#pragma unroll
            for (int i = 0; i < 8; ++i) oacc[i][r] *= alpha;
        }

        // ---- P: C-layout -> A-layout via per-wave LDS round trip (fp32)
#pragma unroll
        for (int r = 0; r < 4; ++r)
#pragma unroll
            for (int n = 0; n < 4; ++n)
                lPw[(quad * 4 + r) * PLD + n * 16 + lrow] = S[n][r];
        // same-wave in-order LDS write->read; no barrier needed

        bf16x8 pfr[2];
#pragma unroll
        for (int s = 0; s < 2; ++s) {
            const float* pp = lPw + lrow * PLD + s * 32 + quad * 8;
#pragma unroll
            for (int j = 0; j < 8; ++j)
                pfr[s][j] = (short)f2bf(pp[j]);
        }

        // ---- O += P V : 8 output d-subtiles, K=64 in 2 steps
#pragma unroll
        for (int o8 = 0; o8 < 8; ++o8) {
#pragma unroll
            for (int s = 0; s < 2; ++s) {
                const bf16x8 vf = *(const bf16x8*)&lV[(o8 * 16 + lrow) * VLD + s * 32 + quad * 8];
                oacc[o8] = __builtin_amdgcn_mfma_f32_16x16x32_bf16(pfr[s], vf, oacc[o8], 0, 0, 0);
            }
        }
    }

    // ---- epilogue: normalize by l and store fp32
    float rl[4];
#pragma unroll
    for (int r = 0; r < 4; ++r) rl[r] = 1.0f / lsum[r];
#pragma unroll
    for (int r = 0; r < 4; ++r) {
        const size_t ob = ((size_t)((b * SQ + q0 + wave * 16 + quad * 4 + r) * HQ + h)) * DH;
#pragma unroll
        for (int o8 = 0; o8 < 8; ++o8)
            out[ob + o8 * 16 + lrow] = oacc[o8][r] * rl[r];
    }
}

extern "C" void kernel_launch(void* const* d_in, const int* in_sizes, int n_in,
                              void* d_out, int out_size, void* d_ws, size_t ws_size,
                              hipStream_t stream)
{
    (void)in_sizes; (void)n_in; (void)out_size; (void)d_ws; (void)ws_size;
    const float* q = (const float*)d_in[0];
    const float* k = (const float*)d_in[1];
    const float* v = (const float*)d_in[2];
    const float* m = (const float*)d_in[3];
    float* o = (float*)d_out;
    dim3 grid(SQ / BM, HQ, B_);
    fa_fwd<<<grid, 256, 0, stream>>>(q, k, v, m, o);
}

// Round 3
// 841.996 us; speedup vs baseline: 1.1979x; 1.1979x over previous
//
#include <hip/hip_runtime.h>
#include <hip/hip_bf16.h>
#include <stdint.h>

// Problem constants (B, Sq, Skv, Hq, Hkv, D) = (2, 2048, 2048, 16, 4, 128)
static constexpr int B_   = 2;
static constexpr int SQ   = 2048;
static constexpr int SKV  = 2048;
static constexpr int HQ   = 16;
static constexpr int HKV  = 4;
static constexpr int DH   = 128;

static constexpr int BM = 64;   // q rows per workgroup (16 per wave x 4 waves)
static constexpr int BN = 64;   // kv cols per iteration

static constexpr int KLD = DH + 8;  // 136: K tile LDS row stride (b128 reads OK)
static constexpr int VLD = BN + 6;  // 70:  Vt row stride: writes 3d%32 -> 2-way free
static constexpr int PLD = BN + 4;  // 68 fp32: P relayout stride (verified free)

#define LOG2E 1.44269504f
static constexpr float SM_SCALE = 0.08838834764831845f;  // 1/sqrt(128)

typedef unsigned short ushort_t;
typedef __attribute__((ext_vector_type(8))) short bf16x8;   // 8 bf16 in 4 VGPRs
typedef __attribute__((ext_vector_type(4))) short bf16x4;   // 4 bf16 in 2 VGPRs
typedef __attribute__((ext_vector_type(4))) float f32x4;

__device__ __forceinline__ ushort_t f2bf(float f) {
    union { float f; unsigned int i; } c; c.f = f;
    unsigned int i = c.i;
    i = i + 0x7FFF + ((i >> 16) & 1);   // RNE (finite values only here)
    return (ushort_t)(i >> 16);
}
__device__ __forceinline__ unsigned int f2bf2(float lo, float hi) {
    return (unsigned int)f2bf(lo) | ((unsigned int)f2bf(hi) << 16);
}

extern "C" __global__ __launch_bounds__(256, 2)
void fa_fwd(const float* __restrict__ q, const float* __restrict__ k,
            const float* __restrict__ v, const float* __restrict__ mask,
            float* __restrict__ out)
{
    __shared__ __align__(16) ushort_t lK[BN * KLD];       // K tile bf16, row-major [kv][d]
    __shared__ __align__(16) ushort_t lV[DH * VLD];       // V tile bf16, transposed [d][kv]
    __shared__ __align__(16) float    lP[4 * 16 * PLD];   // per-wave P relayout buffers

    const int bh   = blockIdx.x;
    const int h    = bh & 15;
    const int b    = bh >> 4;
    const int qblk = 31 - blockIdx.y;        // heavy (many-tile) blocks dispatch first
    const int hk   = h & (HKV - 1);          // GQA head map: h % Hkv
    const int tid  = threadIdx.x;
    const int wave = tid >> 6;
    const int lane = tid & 63;
    const int lrow = lane & 15;              // M/N index inside MFMA tile
    const int quad = lane >> 4;
    const int q0   = qblk * BM;

    // ---- Q fragments (A-operand layout): Q[q0+wave*16+lrow][32*s + quad*8 + j]
    const size_t qbase = ((size_t)((b * SQ + q0 + wave * 16 + lrow) * HQ + h)) * DH;
    bf16x8 qf[4];
#pragma unroll
    for (int s = 0; s < 4; ++s) {
        const f32x4 a = *(const f32x4*)(q + qbase + s * 32 + quad * 8);
        const f32x4 c = *(const f32x4*)(q + qbase + s * 32 + quad * 8 + 4);
#pragma unroll
        for (int j = 0; j < 4; ++j) {
            qf[s][j]     = (short)f2bf(a[j]);
            qf[s][j + 4] = (short)f2bf(c[j]);
        }
    }

    f32x4 oacc[8];
#pragma unroll
    for (int i = 0; i < 8; ++i) oacc[i] = (f32x4){0.f, 0.f, 0.f, 0.f};
    float mrow[4] = {-1e30f, -1e30f, -1e30f, -1e30f};
    float lsum[4] = {0.f, 0.f, 0.f, 0.f};

    float* lPw = lP + wave * 16 * PLD;

    // staging index precompute
    const int vd  = tid & 127;               // d for V staging (coalesced across lanes)
    const int vkg = tid >> 7;                // 0..1

    const int niter = qblk + 1;              // causal: kv tiles 0..q0/BN
    for (int it = 0; it < niter; ++it) {
        const int kv0 = it * BN;

        __syncthreads();  // protect previous tile's LDS reads before overwrite

        // ---- stage K row-major (f32x4 loads -> bf16x4 LDS writes)
#pragma unroll
        for (int i = 0; i < 8; ++i) {
            const int idx = tid + i * 256;
            const int r = idx >> 5;                // kv row 0..63
            const int c = (idx & 31) * 4;          // d offset 0..124
            const size_t g = ((size_t)((b * SKV + kv0 + r) * HKV + hk)) * DH + c;
            const f32x4 kx = *(const f32x4*)(k + g);
            bf16x4 kb;
#pragma unroll
            for (int j = 0; j < 4; ++j) kb[j] = (short)f2bf(kx[j]);
            *(bf16x4*)&lK[r * KLD + c] = kb;
        }
        // ---- stage V transposed, d-major: lanes sweep d (coalesced), write along kv
#pragma unroll
        for (int gstep = 0; gstep < 8; ++gstep) {
            const int kvl = (vkg + 2 * gstep) * 4;     // local kv 0..60 step 4
            const size_t gb = ((size_t)((b * SKV + kv0 + kvl) * HKV + hk)) * DH + vd;
            float v0 = v[gb];
            float v1 = v[gb + (size_t)HKV * DH];
            float v2 = v[gb + (size_t)2 * HKV * DH];
            float v3 = v[gb + (size_t)3 * HKV * DH];
            unsigned int* dst = (unsigned int*)&lV[vd * VLD + kvl];
            dst[0] = f2bf2(v0, v1);
            dst[1] = f2bf2(v2, v3);
        }
        __syncthreads();

        // ---- prefetch mask tile values (overlaps with MFMA below)
        const bool diag = (kv0 == q0);
        float mv[4][4];
#pragma unroll
        for (int r = 0; r < 4; ++r) {
            const int row = q0 + wave * 16 + quad * 4 + r;
            const float* mp = mask + ((size_t)(b * HQ + h) * SQ + row) * SKV + kv0;
#pragma unroll
            for (int n = 0; n < 4; ++n)
                mv[r][n] = mp[n * 16 + lrow];
        }

        // ---- S = Q K^T : 16 rows x 64 cols per wave (4 n-subtiles, K=128 in 4 steps)
        f32x4 S[4];
#pragma unroll
        for (int n = 0; n < 4; ++n) {
            f32x4 acc = (f32x4){0.f, 0.f, 0.f, 0.f};
#pragma unroll
            for (int s = 0; s < 4; ++s) {
                const bf16x8 kf = *(const bf16x8*)&lK[(n * 16 + lrow) * KLD + s * 32 + quad * 8];
                acc = __builtin_amdgcn_mfma_f32_16x16x32_bf16(qf[s], kf, acc, 0, 0, 0);
            }
            S[n] = acc;
        }

        // ---- scale + additive mask (+ causal bias on diagonal tile), exp2 space
#pragma unroll
        for (int r = 0; r < 4; ++r) {
            const int row = q0 + wave * 16 + quad * 4 + r;
#pragma unroll
            for (int n = 0; n < 4; ++n) {
                const int col = n * 16 + lrow;
                float s2 = S[n][r] * (SM_SCALE * LOG2E) + mv[r][n] * LOG2E;
                if (diag && (kv0 + col > row)) s2 -= 1000000.0f;
                S[n][r] = s2;
            }
        }

        // ---- online softmax (each row lives across the 16 lanes of one quad)
#pragma unroll
        for (int r = 0; r < 4; ++r) {
            float tm = fmaxf(fmaxf(S[0][r], S[1][r]), fmaxf(S[2][r], S[3][r]));
#pragma unroll
            for (int off = 1; off < 16; off <<= 1)
                tm = fmaxf(tm, __shfl_xor(tm, off, 64));
            const float mnew  = fmaxf(mrow[r], tm);
            const float alpha = exp2f(mrow[r] - mnew);
            mrow[r] = mnew;
            float psum = 0.f;
#pragma unroll
            for (int n = 0; n < 4; ++n) {
                const float p = exp2f(S[n][r] - mnew);
                S[n][r] = p;
                psum += p;
            }
#pragma unroll
            for (int off = 1; off < 16; off <<= 1)
                psum += __shfl_xor(psum, off, 64);
            lsum[r] = lsum[r] * alpha + psum;
#pragma unroll
            for (int i = 0; i < 8; ++i) oacc[i][r] *= alpha;
        }

        // ---- P: C-layout -> A-layout via per-wave LDS round trip (fp32, conflict-free)
#pragma unroll
        for (int r = 0; r < 4; ++r)
#pragma unroll
            for (int n = 0; n < 4; ++n)
                lPw[(quad * 4 + r) * PLD + n * 16 + lrow] = S[n][r];
        // same-wave in-order LDS write->read; no barrier needed

        bf16x8 pfr[2];
#pragma unroll
        for (int s = 0; s < 2; ++s) {
            const float* pp = lPw + lrow * PLD + s * 32 + quad * 8;
#pragma unroll
            for (int j = 0; j < 8; ++j)
                pfr[s][j] = (short)f2bf(pp[j]);
        }

        // ---- O += P V : 8 output d-subtiles, K=64 in 2 steps
#pragma unroll
        for (int o8 = 0; o8 < 8; ++o8) {
#pragma unroll
            for (int s = 0; s < 2; ++s) {
                const ushort_t* vp = &lV[(o8 * 16 + lrow) * VLD + s * 32 + quad * 8];
                union { bf16x8 v; unsigned int u[4]; } vf;
#pragma unroll
                for (int u2 = 0; u2 < 4; ++u2)
                    vf.u[u2] = *(const unsigned int*)(vp + 2 * u2);
                oacc[o8] = __builtin_amdgcn_mfma_f32_16x16x32_bf16(pfr[s], vf.v, oacc[o8], 0, 0, 0);
            }
        }
    }

    // ---- epilogue: normalize by l and store fp32
    float rl[4];
#pragma unroll
    for (int r = 0; r < 4; ++r) rl[r] = 1.0f / lsum[r];
#pragma unroll
    for (int r = 0; r < 4; ++r) {
        const size_t ob = ((size_t)((b * SQ + q0 + wave * 16 + quad * 4 + r) * HQ + h)) * DH;
#pragma unroll
        for (int o8 = 0; o8 < 8; ++o8)
            out[ob + o8 * 16 + lrow] = oacc[o8][r] * rl[r];
    }
}

extern "C" void kernel_launch(void* const* d_in, const int* in_sizes, int n_in,
                              void* d_out, int out_size, void* d_ws, size_t ws_size,
                              hipStream_t stream)
{
    (void)in_sizes; (void)n_in; (void)out_size; (void)d_ws; (void)ws_size;
    const float* q = (const float*)d_in[0];
    const float* k = (const float*)d_in[1];
    const float* v = (const float*)d_in[2];
    const float* m = (const float*)d_in[3];
    float* o = (float*)d_out;
    dim3 grid(B_ * HQ, SQ / BM, 1);
    fa_fwd<<<grid, 256, 0, stream>>>(q, k, v, m, o);
}